// Round 1
// baseline (108.340 us; speedup 1.0000x reference)
//
#include <hip/hip_runtime.h>
#include <hip/hip_bf16.h>

// GlobalPointer logits: x = inputs@W+b -> split q/k per head -> RoPE(q) ->
// logits[b,h,m,n] = <q[b,m,h,:], k[b,n,h,:]> with mask+causal, /8.
// B=8 S=512 DIM=768 H=24 D=64. Output [8][24][512][512] f32.

typedef __bf16 bf16_t;
typedef __attribute__((ext_vector_type(8))) __bf16 bf16x8;
typedef __attribute__((ext_vector_type(4))) float f32x4;

#define NEG_INF 1000000000000.0f

// ws layout (bytes)
#define WS_A   0                  // inputs bf16 [4096][768]   : 6,291,456
#define WS_WT  6291456            // W^T bf16 [3072][768]      : 4,718,592
#define WS_Q   11010048           // Q bf16 [8][24][512][64]   : 12,582,912
#define WS_K   23592960           // K bf16 [8][24][512][64]   : 12,582,912
// total 36,175,872 bytes

__device__ __forceinline__ unsigned short f2bf_bits(float x) {
  union { float f; unsigned u; } v; v.f = x;
  unsigned r = v.u + 0x7FFFu + ((v.u >> 16) & 1u);
  return (unsigned short)(r >> 16);
}

#define GLD16(g, l) __builtin_amdgcn_global_load_lds( \
    (const __attribute__((address_space(1))) void*)(g), \
    (__attribute__((address_space(3))) void*)(l), 16, 0, 0)

// ---------------- conversion kernels ----------------

__global__ void conv_inputs_kernel(const float4* __restrict__ in,
                                   ushort4* __restrict__ out, int n4) {
  int i = blockIdx.x * blockDim.x + threadIdx.x;
  if (i < n4) {
    float4 v = in[i];
    ushort4 o;
    o.x = f2bf_bits(v.x); o.y = f2bf_bits(v.y);
    o.z = f2bf_bits(v.z); o.w = f2bf_bits(v.w);
    out[i] = o;
  }
}

// W [768][3072] f32 -> Wt [3072][768] bf16 (32x32 LDS tile transpose)
__global__ void conv_wt_kernel(const float* __restrict__ W,
                               unsigned short* __restrict__ Wt) {
  __shared__ float s[32][33];
  int tx = threadIdx.x & 31, ty = threadIdx.x >> 5; // ty 0..7
  int n0 = blockIdx.x * 32, k0 = blockIdx.y * 32;
#pragma unroll
  for (int r = 0; r < 4; ++r) {
    int k = k0 + ty + r * 8;
    s[ty + r * 8][tx] = W[(size_t)k * 3072 + n0 + tx];
  }
  __syncthreads();
#pragma unroll
  for (int r = 0; r < 4; ++r) {
    int n = ty + r * 8;
    Wt[(size_t)(n0 + n) * 768 + k0 + tx] = f2bf_bits(s[tx][n]);
  }
}

// ---------------- GEMM1: X = A(4096x768) * Wt^T(3072x768), +bias, RoPE(q), split ----------------
// 128x128 tile, 4 waves (2x2 of 64x64), BK=32, mfma 16x16x32 bf16.
// LDS staged via global_load_lds with pre-swizzled source (slot ^= (row>>1)&3).
__global__ __launch_bounds__(256) void gemm1_kernel(
    const bf16_t* __restrict__ A, const bf16_t* __restrict__ Bt,
    const float* __restrict__ bias,
    unsigned short* __restrict__ Qo, unsigned short* __restrict__ Ko) {
  __shared__ __align__(16) bf16_t As[128 * 32];
  __shared__ __align__(16) bf16_t Bs[128 * 32];
  const int tid = threadIdx.x;
  const int lane = tid & 63;
  const int wv = tid >> 6;
  const int wr = (wv >> 1) * 64;
  const int wc = (wv & 1) * 64;
  const int m0 = blockIdx.y * 128;
  const int n0 = blockIdx.x * 128;

  f32x4 acc[4][4];
#pragma unroll
  for (int i = 0; i < 4; ++i)
#pragma unroll
    for (int j = 0; j < 4; ++j) acc[i][j] = (f32x4){0.f, 0.f, 0.f, 0.f};

  const int srow = lane >> 2;   // row within 16-row chunk
  const int sslot = lane & 3;   // 16B slot within 64B row

  for (int k0 = 0; k0 < 768; k0 += 32) {
#pragma unroll
    for (int i = 0; i < 2; ++i) {
      int c = 2 * wv + i;               // chunk 0..7 (16 rows each)
      int row = 16 * c + srow;
      int fslot = sslot ^ ((row >> 1) & 3);   // pre-swizzled source
      const bf16_t* ga = A + (size_t)(m0 + row) * 768 + k0 + fslot * 8;
      const bf16_t* gb = Bt + (size_t)(n0 + row) * 768 + k0 + fslot * 8;
      GLD16(ga, As + c * 512);
      GLD16(gb, Bs + c * 512);
    }
    __syncthreads();

    const int kslot = lane >> 4;
    bf16x8 af[4], bfr[4];
#pragma unroll
    for (int m16 = 0; m16 < 4; ++m16) {
      int arow = wr + m16 * 16 + (lane & 15);
      int sl = kslot ^ ((arow >> 1) & 3);     // swizzled read
      af[m16] = *(const bf16x8*)(As + arow * 32 + sl * 8);
    }
#pragma unroll
    for (int n16 = 0; n16 < 4; ++n16) {
      int brow = wc + n16 * 16 + (lane & 15);
      int sl = kslot ^ ((brow >> 1) & 3);
      bfr[n16] = *(const bf16x8*)(Bs + brow * 32 + sl * 8);
    }
#pragma unroll
    for (int m16 = 0; m16 < 4; ++m16)
#pragma unroll
      for (int n16 = 0; n16 < 4; ++n16)
        acc[m16][n16] = __builtin_amdgcn_mfma_f32_16x16x32_bf16(
            af[m16], bfr[n16], acc[m16][n16], 0, 0, 0);
    __syncthreads();
  }

  // epilogue: +bias, RoPE on q half, write bf16 Q / K in [b][h][s][64]
  const int h = blockIdx.x;  // exactly one head (128 cols) per n-block
#pragma unroll
  for (int n16 = 0; n16 < 4; ++n16) {
    int c = wc + n16 * 16 + (lane & 15);     // 0..127 within head
    float bv = bias[h * 128 + c];
    bool isq = (c < 64);
    int d = isq ? c : (c - 64);
    float inv = exp2f((float)((c >> 1) & 31) * -0.4152410118609203f); // 10000^(-i/32)
#pragma unroll
    for (int m16 = 0; m16 < 4; ++m16) {
      int rbase = m0 + wr + m16 * 16 + ((lane >> 4) * 4);
#pragma unroll
      for (int r = 0; r < 4; ++r) {
        int mg = rbase + r;
        int s = mg & 511, b = mg >> 9;
        float val = acc[m16][n16][r] + bv;
        float other = __shfl_xor(val, 1, 64);  // partner column c^1 (lane^1)
        float res;
        if (isq) {
          float ang = (float)s * inv;
          float sn, cs;
          sincosf(ang, &sn, &cs);
          res = val * cs + ((c & 1) ? other : -other) * sn;
        } else {
          res = val;
        }
        size_t off = (((size_t)(b * 24 + h) * 512) + s) * 64 + d;
        (isq ? Qo : Ko)[off] = f2bf_bits(res);
      }
    }
  }
}

// ---------------- GEMM2: logits[bh] = Q(512x64) * K^T, mask/causal/scale ----------------
// Per block: 128x128 tile of one (b,h). K=64 in one shot (2 mfma k-steps).
__global__ __launch_bounds__(256) void gemm2_kernel(
    const bf16_t* __restrict__ Q, const bf16_t* __restrict__ K,
    const float* __restrict__ mask, float* __restrict__ out) {
  __shared__ __align__(16) bf16_t Qs[128 * 64];
  __shared__ __align__(16) bf16_t Ks[128 * 64];
  const int tid = threadIdx.x;
  const int lane = tid & 63;
  const int wv = tid >> 6;
  const int wr = (wv >> 1) * 64;
  const int wc = (wv & 1) * 64;
  const int bh = blockIdx.z;
  const int b = bh / 24;
  const int m0 = blockIdx.y * 128;
  const int n0 = blockIdx.x * 128;
  const size_t base = (size_t)bh * 512 * 64;

  const int srow = lane >> 3;  // row within 8-row chunk (128B rows)
  const int sslot = lane & 7;
#pragma unroll
  for (int i = 0; i < 4; ++i) {
    int c = 4 * wv + i;                 // chunk 0..15 (8 rows each)
    int row = 8 * c + srow;
    int fslot = sslot ^ (row & 7);      // pre-swizzled source
    const bf16_t* gq = Q + base + (size_t)(m0 + row) * 64 + fslot * 8;
    const bf16_t* gk = K + base + (size_t)(n0 + row) * 64 + fslot * 8;
    GLD16(gq, Qs + c * 512);
    GLD16(gk, Ks + c * 512);
  }
  __syncthreads();

  f32x4 acc[4][4];
#pragma unroll
  for (int i = 0; i < 4; ++i)
#pragma unroll
    for (int j = 0; j < 4; ++j) acc[i][j] = (f32x4){0.f, 0.f, 0.f, 0.f};

#pragma unroll
  for (int kk = 0; kk < 2; ++kk) {
    const int kslot = (lane >> 4) + kk * 4;
    bf16x8 af[4], bfr[4];
#pragma unroll
    for (int m16 = 0; m16 < 4; ++m16) {
      int arow = wr + m16 * 16 + (lane & 15);
      int sl = kslot ^ (arow & 7);
      af[m16] = *(const bf16x8*)(Qs + arow * 64 + sl * 8);
    }
#pragma unroll
    for (int n16 = 0; n16 < 4; ++n16) {
      int brow = wc + n16 * 16 + (lane & 15);
      int sl = kslot ^ (brow & 7);
      bfr[n16] = *(const bf16x8*)(Ks + brow * 64 + sl * 8);
    }
#pragma unroll
    for (int m16 = 0; m16 < 4; ++m16)
#pragma unroll
      for (int n16 = 0; n16 < 4; ++n16)
        acc[m16][n16] = __builtin_amdgcn_mfma_f32_16x16x32_bf16(
            af[m16], bfr[n16], acc[m16][n16], 0, 0, 0);
  }

  const float* mb = mask + (size_t)b * 512;
  float* ob = out + (size_t)bh * 512 * 512;
#pragma unroll
  for (int m16 = 0; m16 < 4; ++m16) {
    int mgb = m0 + wr + m16 * 16 + ((lane >> 4) * 4);
    float mr[4];
#pragma unroll
    for (int r = 0; r < 4; ++r) mr[r] = mb[mgb + r];
#pragma unroll
    for (int n16 = 0; n16 < 4; ++n16) {
      int ng = n0 + wc + n16 * 16 + (lane & 15);
      float mc = mb[ng];
#pragma unroll
      for (int r = 0; r < 4; ++r) {
        int mg = mgb + r;
        float v = acc[m16][n16][r];
        v = v * mr[r] - NEG_INF * (1.0f - mr[r]);
        v = v * mc - NEG_INF * (1.0f - mc);
        if (mg > ng) v -= NEG_INF;   // tril(-1) causal
        v *= 0.125f;                 // / sqrt(64)
        ob[(size_t)mg * 512 + ng] = v;
      }
    }
  }
}

extern "C" void kernel_launch(void* const* d_in, const int* in_sizes, int n_in,
                              void* d_out, int out_size, void* d_ws, size_t ws_size,
                              hipStream_t stream) {
  const float* inputs = (const float*)d_in[0];   // [8][512][768]
  const float* mask = (const float*)d_in[1];     // [8][512]
  const float* W = (const float*)d_in[2];        // [768][3072]
  const float* bias = (const float*)d_in[3];     // [3072]
  float* out = (float*)d_out;                    // [8][24][512][512]
  char* ws = (char*)d_ws;

  bf16_t* Abf = (bf16_t*)(ws + WS_A);
  bf16_t* Wt = (bf16_t*)(ws + WS_WT);
  unsigned short* Qb = (unsigned short*)(ws + WS_Q);
  unsigned short* Kb = (unsigned short*)(ws + WS_K);

  // inputs f32 -> bf16 (3,145,728 elems = 786,432 float4)
  conv_inputs_kernel<<<3072, 256, 0, stream>>>((const float4*)inputs,
                                               (ushort4*)Abf, 786432);
  // W -> W^T bf16
  conv_wt_kernel<<<dim3(96, 24), 256, 0, stream>>>(W, (unsigned short*)Wt);
  // X = A*W^T + b, RoPE, split -> Q,K bf16
  gemm1_kernel<<<dim3(24, 32), 256, 0, stream>>>(Abf, Wt, bias, Qb, Kb);
  // logits
  gemm2_kernel<<<dim3(4, 4, 192), 256, 0, stream>>>((const bf16_t*)Qb,
                                                    (const bf16_t*)Kb, mask, out);
}